// Round 3
// baseline (3546.645 us; speedup 1.0000x reference)
//
#include <hip/hip_runtime.h>
#include <stdint.h>

// MDLSTM2D: B=16, D0=D1=64, F=U=128, 5 gates (f0,f1,i,o,c)
// ROUND 11: R10 (no fence) = 3536us, hop still 27.8us across THREE sync
// structures. Accounting: WRITE=98.8MB == exact sc1 store bytes (write-through
// confirmed); FETCH=234MB < compulsory sc1 read traffic (326MB) -> some
// agent-scope LOADS are served by the local XCD L2. Data reads are
// compulsory-miss (read-once) -> always fresh. But FLAG POLLS re-read one line
// -> can hit a STALE L2 copy; consumer sees the producer's increment only on
// eviction/probe (~22us average). R8's dispatch-end flush played the same role
// (hence identical 29us/diag). FIX: poll via atomic fetch_add(0) - an RMW must
// execute at the coherence point, cannot be served stale. Everything else
// (math, layout, stores, publish) byte-identical to R10.

typedef float f32x2 __attribute__((ext_vector_type(2)));

#define SCOPE_AGENT __HIP_MEMORY_SCOPE_AGENT

__device__ __forceinline__ float sigm(float x) { return 1.f / (1.f + expf(-x)); }

__global__ void zero_flags(uint32_t* __restrict__ flags) {
  flags[blockIdx.x * 256 + threadIdx.x] = 0u;
}

__device__ __forceinline__ void wait_flag4(uint32_t* f) {
  // RMW poll: executes at the coherence point, immune to stale L2 copies.
  while (__hip_atomic_fetch_add(f, 0u, __ATOMIC_RELAXED, SCOPE_AGENT) < 4u)
    __builtin_amdgcn_s_sleep(1);
}

__global__ __launch_bounds__(256, 4) void wavefront_kernel(
    const float* __restrict__ x,
    const float* __restrict__ w0, const float* __restrict__ w1, const float* __restrict__ w2,
    const float* __restrict__ w3, const float* __restrict__ w4,
    const float* __restrict__ u0, const float* __restrict__ u1, const float* __restrict__ u2,
    const float* __restrict__ u3, const float* __restrict__ u4,
    const float* __restrict__ bb0, const float* __restrict__ bb1, const float* __restrict__ bb2,
    const float* __restrict__ bb3, const float* __restrict__ bb4,
    float* __restrict__ hbuf, float* __restrict__ cbuf,
    uint32_t* __restrict__ flags, float* __restrict__ out) {
  __shared__ float xs[16][132];
  __shared__ float hu_l[16][132];
  __shared__ float hl_l[16][132];
  const int tid = threadIdx.x;
  const int b = tid >> 4;          // batch 0..15
  const int pair = tid & 15;       // 2-col group
  const int G = gridDim.x;         // multiple of 4 -> q fixed per block

  // diagonal scan state, monotone across this block's (increasing) task list
  int d = 0, base = 0, cnt4 = 4;   // cnt4 = 4*cells(d); d=0 has 1 cell
  for (int t = blockIdx.x; t < 16384; t += G) {
    while (t >= base + cnt4) {
      base += cnt4;
      ++d;
      const int lo_ = d > 63 ? d - 63 : 0;
      const int hi_ = d < 63 ? d : 63;
      cnt4 = 4 * (hi_ - lo_ + 1);
    }
    const int r = t - base;
    const int lo = d > 63 ? d - 63 : 0;
    const int i = lo + (r >> 2);
    const int q = r & 3;
    const int j = d - i;
    const int cell = (i << 6) + j;
    const size_t cellbase = (size_t)cell * 2048;
    const int n = q * 32 + pair * 2;

    // ---- 1. stage x rows for this cell ----
    for (int idx = tid; idx < 2048; idx += 256) {
      const int bs = idx >> 7, f = idx & 127;
      xs[bs][f] = x[(((size_t)bs * 64 + i) * 64 + j) * 128 + f];
    }
    __syncthreads();

    // ---- 2. projection: P for exactly this thread's 10 outputs (in regs) ----
    float p0a = bb0[n], p0b = bb0[n + 1];
    float p1a = bb1[n], p1b = bb1[n + 1];
    float p2a = bb2[n], p2b = bb2[n + 1];
    float p3a = bb3[n], p3b = bb3[n + 1];
    float p4a = bb4[n], p4b = bb4[n + 1];
    {
      const float* Wp0 = w0 + n;
      const float* Wp1 = w1 + n;
      const float* Wp2 = w2 + n;
      const float* Wp3 = w3 + n;
      const float* Wp4 = w4 + n;
#pragma unroll 4
      for (int f = 0; f < 128; ++f) {
        const float xv = xs[b][f];
        const f32x2 t0 = *(const f32x2*)(Wp0 + f * 128);
        const f32x2 t1 = *(const f32x2*)(Wp1 + f * 128);
        const f32x2 t2 = *(const f32x2*)(Wp2 + f * 128);
        const f32x2 t3 = *(const f32x2*)(Wp3 + f * 128);
        const f32x2 t4 = *(const f32x2*)(Wp4 + f * 128);
        p0a += xv * t0[0]; p0b += xv * t0[1];
        p1a += xv * t1[0]; p1b += xv * t1[1];
        p2a += xv * t2[0]; p2b += xv * t2[1];
        p3a += xv * t3[0]; p3b += xv * t3[1];
        p4a += xv * t4[0]; p4b += xv * t4[1];
      }
    }

    // ---- 3. wait for both neighbor cells (flag==4: all 4 q-blocks done) ----
    if (tid == 0) {
      if (i > 0) wait_flag4(&flags[cell - 64]);
      if (j > 0) wait_flag4(&flags[cell - 1]);
    }
    __syncthreads();

    // ---- 4. stage h_up / h_left via coherent (sc1) loads -> LDS ----
    // (read-once lines: compulsory miss -> always fetched fresh from MALL)
    for (int idx = tid; idx < 1024; idx += 256) {
      const int bs = idx >> 6, k2 = (idx & 63) << 1;
      unsigned long long vu = 0ull, vl = 0ull;
      if (i > 0)
        vu = __hip_atomic_load((const unsigned long long*)(hbuf + cellbase - 64 * 2048 + bs * 128 + k2),
                               __ATOMIC_RELAXED, SCOPE_AGENT);
      if (j > 0)
        vl = __hip_atomic_load((const unsigned long long*)(hbuf + cellbase - 2048 + bs * 128 + k2),
                               __ATOMIC_RELAXED, SCOPE_AGENT);
      *(f32x2*)(&hu_l[bs][k2]) = __builtin_bit_cast(f32x2, vu);
      *(f32x2*)(&hl_l[bs][k2]) = __builtin_bit_cast(f32x2, vl);
    }
    __syncthreads();

    // ---- 5. recurrence: 5 matvecs over k (U cached in L1/L2, never inval'd) ----
    const float* Up0 = u0 + n;
    const float* Up1 = u1 + n;
    const float* Up2 = u2 + n;
    const float* Up3 = u3 + n;
    const float* Up4 = u4 + n;
    float d0a = 0, d0b = 0, d1a = 0, d1b = 0, d2a = 0, d2b = 0;
    float d3a = 0, d3b = 0, d4a = 0, d4b = 0;
#pragma unroll 4
    for (int k = 0; k < 128; ++k) {
      const float a = hu_l[b][k], l = hl_l[b][k], s = a + l;
      const f32x2 t0 = *(const f32x2*)(Up0 + k * 128);
      const f32x2 t1 = *(const f32x2*)(Up1 + k * 128);
      const f32x2 t2 = *(const f32x2*)(Up2 + k * 128);
      const f32x2 t3 = *(const f32x2*)(Up3 + k * 128);
      const f32x2 t4 = *(const f32x2*)(Up4 + k * 128);
      d0a += a * t0[0]; d0b += a * t0[1];
      d1a += l * t1[0]; d1b += l * t1[1];
      d2a += s * t2[0]; d2b += s * t2[1];
      d3a += s * t3[0]; d3b += s * t3[1];
      d4a += s * t4[0]; d4b += s * t4[1];
    }

    // ---- 6. gates + state update ----
    const float f0a = sigm(p0a + d0a), f0b = sigm(p0b + d0b);
    const float f1a = sigm(p1a + d1a), f1b = sigm(p1b + d1b);
    const float ita = sigm(p2a + d2a), itb = sigm(p2b + d2b);
    const float ota = sigm(p3a + d3a), otb = sigm(p3b + d3b);
    const float cpa = tanhf(p4a + d4a), cpb = tanhf(p4b + d4b);
    f32x2 cu = {0.f, 0.f}, cl = {0.f, 0.f};
    if (i > 0)
      cu = __builtin_bit_cast(f32x2,
          __hip_atomic_load((const unsigned long long*)(cbuf + cellbase - 64 * 2048 + b * 128 + n),
                            __ATOMIC_RELAXED, SCOPE_AGENT));
    if (j > 0)
      cl = __builtin_bit_cast(f32x2,
          __hip_atomic_load((const unsigned long long*)(cbuf + cellbase - 2048 + b * 128 + n),
                            __ATOMIC_RELAXED, SCOPE_AGENT));
    const float ca = f0a * cu[0] + f1a * cl[0] + ita * cpa;
    const float cb = f0b * cu[1] + f1b * cl[1] + itb * cpb;
    const float ha = ota * tanhf(ca), hb = otb * tanhf(cb);
    // all stores sc1 write-through: globally visible at vmcnt retire, L2 stays clean
    __hip_atomic_store((unsigned long long*)(cbuf + cellbase + b * 128 + n),
                       __builtin_bit_cast(unsigned long long, (f32x2){ca, cb}),
                       __ATOMIC_RELAXED, SCOPE_AGENT);
    __hip_atomic_store((unsigned long long*)(hbuf + cellbase + b * 128 + n),
                       __builtin_bit_cast(unsigned long long, (f32x2){ha, hb}),
                       __ATOMIC_RELAXED, SCOPE_AGENT);
    __hip_atomic_store((unsigned long long*)(out + (((size_t)b * 64 + i) * 64 + j) * 128 + n),
                       __builtin_bit_cast(unsigned long long, (f32x2){ha, hb}),
                       __ATOMIC_RELAXED, SCOPE_AGENT);

    // ---- 7. publish: barrier drains every wave's vmcnt (all sc1 stores
    // visible at the LLC), then tid0 bumps the flag via RMW. ----
    __syncthreads();
    if (tid == 0) {
      __hip_atomic_fetch_add(&flags[cell], 1u, __ATOMIC_RELAXED, SCOPE_AGENT);
    }
  }
}

extern "C" void kernel_launch(void* const* d_in, const int* in_sizes, int n_in,
                              void* d_out, int out_size, void* d_ws, size_t ws_size,
                              hipStream_t stream) {
  const float* x = (const float*)d_in[0];
  const float* w0 = (const float*)d_in[1];
  const float* u0 = (const float*)d_in[2];
  const float* b0 = (const float*)d_in[3];
  const float* w1 = (const float*)d_in[4];
  const float* u1 = (const float*)d_in[5];
  const float* b1 = (const float*)d_in[6];
  const float* w2 = (const float*)d_in[7];
  const float* u2 = (const float*)d_in[8];
  const float* b2 = (const float*)d_in[9];
  const float* w3 = (const float*)d_in[10];
  const float* u3 = (const float*)d_in[11];
  const float* b3 = (const float*)d_in[12];
  const float* w4 = (const float*)d_in[13];
  const float* u4 = (const float*)d_in[14];
  const float* b4 = (const float*)d_in[15];

  char* ws = (char*)d_ws;
  // layout: flags[4096] u32 (16 KB) ; hbuf 33.55 MB ; cbuf 33.55 MB
  const size_t OFF_FLAGS = 0;
  const size_t OFF_H = 16384;
  const size_t OFF_C = OFF_H + (size_t)4096 * 2048 * 4;
  const size_t OFF_END = OFF_C + (size_t)4096 * 2048 * 4;
  if (ws_size < OFF_END) return;

  uint32_t* flags = (uint32_t*)(ws + OFF_FLAGS);
  float* hbuf = (float*)(ws + OFF_H);
  float* cbuf = (float*)(ws + OFF_C);
  float* out = (float*)d_out;

  // pick a guaranteed-co-resident grid once (multiple of 4 -> fixed q/block)
  static int grid = 0;
  if (grid == 0) {
    int dev = 0;
    hipGetDevice(&dev);
    int cus = 0;
    hipDeviceGetAttribute(&cus, hipDeviceAttributeMultiprocessorCount, dev);
    int per_cu = 0;
    hipOccupancyMaxActiveBlocksPerMultiprocessor(&per_cu, (const void*)wavefront_kernel, 256, 0);
    if (cus <= 0) cus = 256;
    if (per_cu <= 0) per_cu = 1;
    long g = (long)cus * (long)per_cu;
    if (g > 2048) g = 2048;
    g &= ~3L;
    if (g < 4) g = 4;
    grid = (int)g;
  }

  hipLaunchKernelGGL(zero_flags, dim3(16), dim3(256), 0, stream, flags);

  void* args[] = {(void*)&x,  (void*)&w0, (void*)&w1, (void*)&w2, (void*)&w3, (void*)&w4,
                  (void*)&u0, (void*)&u1, (void*)&u2, (void*)&u3, (void*)&u4,
                  (void*)&b0, (void*)&b1, (void*)&b2, (void*)&b3, (void*)&b4,
                  (void*)&hbuf, (void*)&cbuf, (void*)&flags, (void*)&out};
  hipError_t e = hipLaunchCooperativeKernel((const void*)wavefront_kernel, dim3(grid),
                                            dim3(256), args, 0, stream);
  if (e != hipSuccess) {
    (void)hipGetLastError();  // clear; fall back to plain launch (grid <= capacity)
    wavefront_kernel<<<grid, 256, 0, stream>>>(x, w0, w1, w2, w3, w4, u0, u1, u2, u3, u4,
                                               b0, b1, b2, b3, b4, hbuf, cbuf, flags, out);
  }
}

// Round 4
// 3461.673 us; speedup vs baseline: 1.0245x; 1.0245x over previous
//
#include <hip/hip_runtime.h>
#include <stdint.h>

// MDLSTM2D: B=16, D0=D1=64, F=U=128, 5 gates (f0,f1,i,o,c)
// ROUND 12: R9/R10/R11 all ~3.5-3.7ms with hop ~28us across four sync
// structures. Unified theory: EVERY resident block (~2048) polls the few
// cache lines holding the wavefront's flags (64 flags = 4 lines/diagonal).
// RMWs to one line serialize at the MALL bank: ~500 pollers/line x ~20ns
// service => ~10us poll round-trip, and the producer's critical flag++
// QUEUES BEHIND the same backlog (~+10us). Load-polls (R10) contend the
// same way => same time (and R8's dispatch flush was the same order).
// FIX: private mailboxes. Task->block map is static, so each producer task
// signals its <=8 consumer tasks directly: per-task 64B-strided mailbox
// (1MB region); producer tids 0..7 fetch_add(1) to 8 DISTINCT lines after
// the drain barrier; consumer tid0 polls ITS OWN line (1 poller/line) until
// 4*ndeps signals. No shared sync lines anywhere. Math/layout unchanged.

typedef float f32x2 __attribute__((ext_vector_type(2)));

#define SCOPE_AGENT __HIP_MEMORY_SCOPE_AGENT

__device__ __forceinline__ float sigm(float x) { return 1.f / (1.f + expf(-x)); }

__global__ void zero_mbox(uint32_t* __restrict__ mbox) {
  // 16384 mailboxes x 64B = 1MB = 262144 u32
  for (int w = blockIdx.x * 256 + threadIdx.x; w < 262144; w += 256 * 256)
    mbox[w] = 0u;
}

__global__ __launch_bounds__(256, 4) void wavefront_kernel(
    const float* __restrict__ x,
    const float* __restrict__ w0, const float* __restrict__ w1, const float* __restrict__ w2,
    const float* __restrict__ w3, const float* __restrict__ w4,
    const float* __restrict__ u0, const float* __restrict__ u1, const float* __restrict__ u2,
    const float* __restrict__ u3, const float* __restrict__ u4,
    const float* __restrict__ bb0, const float* __restrict__ bb1, const float* __restrict__ bb2,
    const float* __restrict__ bb3, const float* __restrict__ bb4,
    float* __restrict__ hbuf, float* __restrict__ cbuf,
    uint32_t* __restrict__ mbox, float* __restrict__ out) {
  __shared__ float xs[16][132];
  __shared__ float hu_l[16][132];
  __shared__ float hl_l[16][132];
  const int tid = threadIdx.x;
  const int b = tid >> 4;          // batch 0..15
  const int pair = tid & 15;       // 2-col group
  const int G = gridDim.x;         // multiple of 4 -> q fixed per block

  // diagonal scan state, monotone across this block's (increasing) task list
  int d = 0, base = 0, cnt4 = 4;   // cnt4 = 4*cells(d); d=0 has 1 cell
  for (int t = blockIdx.x; t < 16384; t += G) {
    while (t >= base + cnt4) {
      base += cnt4;
      ++d;
      const int lo_ = d > 63 ? d - 63 : 0;
      const int hi_ = d < 63 ? d : 63;
      cnt4 = 4 * (hi_ - lo_ + 1);
    }
    const int r = t - base;
    const int lo = d > 63 ? d - 63 : 0;
    const int i = lo + (r >> 2);
    const int q = r & 3;
    const int j = d - i;
    const int cell = (i << 6) + j;
    const size_t cellbase = (size_t)cell * 2048;
    const int n = q * 32 + pair * 2;

    // ---- 1. stage x rows for this cell ----
    for (int idx = tid; idx < 2048; idx += 256) {
      const int bs = idx >> 7, f = idx & 127;
      xs[bs][f] = x[(((size_t)bs * 64 + i) * 64 + j) * 128 + f];
    }
    __syncthreads();

    // ---- 2. projection: P for exactly this thread's 10 outputs (in regs) ----
    // (runs in the spin shadow: this block's deps are ~G/256 diagonals away)
    float p0a = bb0[n], p0b = bb0[n + 1];
    float p1a = bb1[n], p1b = bb1[n + 1];
    float p2a = bb2[n], p2b = bb2[n + 1];
    float p3a = bb3[n], p3b = bb3[n + 1];
    float p4a = bb4[n], p4b = bb4[n + 1];
    {
      const float* Wp0 = w0 + n;
      const float* Wp1 = w1 + n;
      const float* Wp2 = w2 + n;
      const float* Wp3 = w3 + n;
      const float* Wp4 = w4 + n;
#pragma unroll 4
      for (int f = 0; f < 128; ++f) {
        const float xv = xs[b][f];
        const f32x2 t0 = *(const f32x2*)(Wp0 + f * 128);
        const f32x2 t1 = *(const f32x2*)(Wp1 + f * 128);
        const f32x2 t2 = *(const f32x2*)(Wp2 + f * 128);
        const f32x2 t3 = *(const f32x2*)(Wp3 + f * 128);
        const f32x2 t4 = *(const f32x2*)(Wp4 + f * 128);
        p0a += xv * t0[0]; p0b += xv * t0[1];
        p1a += xv * t1[0]; p1b += xv * t1[1];
        p2a += xv * t2[0]; p2b += xv * t2[1];
        p3a += xv * t3[0]; p3b += xv * t3[1];
        p4a += xv * t4[0]; p4b += xv * t4[1];
      }
    }

    // ---- 3. wait on OWN mailbox: 4 signals per existing dep cell ----
    const int ndeps = (i > 0) + (j > 0);
    if (tid == 0 && ndeps) {
      uint32_t* mb = &mbox[(size_t)t * 16];
      const uint32_t need = 4u * (uint32_t)ndeps;
      while (__hip_atomic_fetch_add(mb, 0u, __ATOMIC_RELAXED, SCOPE_AGENT) < need)
        __builtin_amdgcn_s_sleep(2);
    }
    __syncthreads();

    // ---- 4. stage h_up / h_left via coherent (sc1) loads -> LDS ----
    for (int idx = tid; idx < 1024; idx += 256) {
      const int bs = idx >> 6, k2 = (idx & 63) << 1;
      unsigned long long vu = 0ull, vl = 0ull;
      if (i > 0)
        vu = __hip_atomic_load((const unsigned long long*)(hbuf + cellbase - 64 * 2048 + bs * 128 + k2),
                               __ATOMIC_RELAXED, SCOPE_AGENT);
      if (j > 0)
        vl = __hip_atomic_load((const unsigned long long*)(hbuf + cellbase - 2048 + bs * 128 + k2),
                               __ATOMIC_RELAXED, SCOPE_AGENT);
      *(f32x2*)(&hu_l[bs][k2]) = __builtin_bit_cast(f32x2, vu);
      *(f32x2*)(&hl_l[bs][k2]) = __builtin_bit_cast(f32x2, vl);
    }
    __syncthreads();

    // ---- 5. recurrence: 5 matvecs over k (U stays L2-resident) ----
    const float* Up0 = u0 + n;
    const float* Up1 = u1 + n;
    const float* Up2 = u2 + n;
    const float* Up3 = u3 + n;
    const float* Up4 = u4 + n;
    float d0a = 0, d0b = 0, d1a = 0, d1b = 0, d2a = 0, d2b = 0;
    float d3a = 0, d3b = 0, d4a = 0, d4b = 0;
#pragma unroll 4
    for (int k = 0; k < 128; ++k) {
      const float a = hu_l[b][k], l = hl_l[b][k], s = a + l;
      const f32x2 t0 = *(const f32x2*)(Up0 + k * 128);
      const f32x2 t1 = *(const f32x2*)(Up1 + k * 128);
      const f32x2 t2 = *(const f32x2*)(Up2 + k * 128);
      const f32x2 t3 = *(const f32x2*)(Up3 + k * 128);
      const f32x2 t4 = *(const f32x2*)(Up4 + k * 128);
      d0a += a * t0[0]; d0b += a * t0[1];
      d1a += l * t1[0]; d1b += l * t1[1];
      d2a += s * t2[0]; d2b += s * t2[1];
      d3a += s * t3[0]; d3b += s * t3[1];
      d4a += s * t4[0]; d4b += s * t4[1];
    }

    // ---- 6. gates + state update ----
    const float f0a = sigm(p0a + d0a), f0b = sigm(p0b + d0b);
    const float f1a = sigm(p1a + d1a), f1b = sigm(p1b + d1b);
    const float ita = sigm(p2a + d2a), itb = sigm(p2b + d2b);
    const float ota = sigm(p3a + d3a), otb = sigm(p3b + d3b);
    const float cpa = tanhf(p4a + d4a), cpb = tanhf(p4b + d4b);
    f32x2 cu = {0.f, 0.f}, cl = {0.f, 0.f};
    if (i > 0)
      cu = __builtin_bit_cast(f32x2,
          __hip_atomic_load((const unsigned long long*)(cbuf + cellbase - 64 * 2048 + b * 128 + n),
                            __ATOMIC_RELAXED, SCOPE_AGENT));
    if (j > 0)
      cl = __builtin_bit_cast(f32x2,
          __hip_atomic_load((const unsigned long long*)(cbuf + cellbase - 2048 + b * 128 + n),
                            __ATOMIC_RELAXED, SCOPE_AGENT));
    const float ca = f0a * cu[0] + f1a * cl[0] + ita * cpa;
    const float cb = f0b * cu[1] + f1b * cl[1] + itb * cpb;
    const float ha = ota * tanhf(ca), hb = otb * tanhf(cb);
    // sc1 write-through: globally visible at vmcnt retire, L2 stays clean
    __hip_atomic_store((unsigned long long*)(cbuf + cellbase + b * 128 + n),
                       __builtin_bit_cast(unsigned long long, (f32x2){ca, cb}),
                       __ATOMIC_RELAXED, SCOPE_AGENT);
    __hip_atomic_store((unsigned long long*)(hbuf + cellbase + b * 128 + n),
                       __builtin_bit_cast(unsigned long long, (f32x2){ha, hb}),
                       __ATOMIC_RELAXED, SCOPE_AGENT);
    __hip_atomic_store((unsigned long long*)(out + (((size_t)b * 64 + i) * 64 + j) * 128 + n),
                       __builtin_bit_cast(unsigned long long, (f32x2){ha, hb}),
                       __ATOMIC_RELAXED, SCOPE_AGENT);

    // ---- 7. publish: barrier drains vmcnt (stores visible), then tids 0..7
    // signal the <=8 consumer tasks' PRIVATE mailboxes in parallel ----
    __syncthreads();
    if (tid < 8 && d < 126) {
      const bool down = tid < 4;           // consumer (i+1,j) vs (i,j+1)
      const int qq = tid & 3;
      if ((down && i < 63) || (!down && j < 63)) {
        const int lo_next = (d + 1) > 63 ? (d + 1) - 63 : 0;
        const int base_next = base + cnt4;  // task base of diagonal d+1
        const int row = down ? (i + 1) : i;
        const int ct = base_next + 4 * (row - lo_next) + qq;
        __hip_atomic_fetch_add(&mbox[(size_t)ct * 16], 1u, __ATOMIC_RELAXED, SCOPE_AGENT);
      }
    }
  }
}

extern "C" void kernel_launch(void* const* d_in, const int* in_sizes, int n_in,
                              void* d_out, int out_size, void* d_ws, size_t ws_size,
                              hipStream_t stream) {
  const float* x = (const float*)d_in[0];
  const float* w0 = (const float*)d_in[1];
  const float* u0 = (const float*)d_in[2];
  const float* b0 = (const float*)d_in[3];
  const float* w1 = (const float*)d_in[4];
  const float* u1 = (const float*)d_in[5];
  const float* b1 = (const float*)d_in[6];
  const float* w2 = (const float*)d_in[7];
  const float* u2 = (const float*)d_in[8];
  const float* b2 = (const float*)d_in[9];
  const float* w3 = (const float*)d_in[10];
  const float* u3 = (const float*)d_in[11];
  const float* b3 = (const float*)d_in[12];
  const float* w4 = (const float*)d_in[13];
  const float* u4 = (const float*)d_in[14];
  const float* b4 = (const float*)d_in[15];

  char* ws = (char*)d_ws;
  // layout: mbox 16384x64B = 1MB ; hbuf 33.55MB ; cbuf 33.55MB
  const size_t OFF_MBOX = 0;
  const size_t OFF_H = 1048576;
  const size_t OFF_C = OFF_H + (size_t)4096 * 2048 * 4;
  const size_t OFF_END = OFF_C + (size_t)4096 * 2048 * 4;
  if (ws_size < OFF_END) return;

  uint32_t* mbox = (uint32_t*)(ws + OFF_MBOX);
  float* hbuf = (float*)(ws + OFF_H);
  float* cbuf = (float*)(ws + OFF_C);
  float* out = (float*)d_out;

  // pick a guaranteed-co-resident grid once (multiple of 4 -> fixed q/block)
  static int grid = 0;
  if (grid == 0) {
    int dev = 0;
    hipGetDevice(&dev);
    int cus = 0;
    hipDeviceGetAttribute(&cus, hipDeviceAttributeMultiprocessorCount, dev);
    int per_cu = 0;
    hipOccupancyMaxActiveBlocksPerMultiprocessor(&per_cu, (const void*)wavefront_kernel, 256, 0);
    if (cus <= 0) cus = 256;
    if (per_cu <= 0) per_cu = 1;
    long g = (long)cus * (long)per_cu;
    if (g > 2048) g = 2048;
    g &= ~3L;
    if (g < 4) g = 4;
    grid = (int)g;
  }

  hipLaunchKernelGGL(zero_mbox, dim3(256), dim3(256), 0, stream, mbox);

  void* args[] = {(void*)&x,  (void*)&w0, (void*)&w1, (void*)&w2, (void*)&w3, (void*)&w4,
                  (void*)&u0, (void*)&u1, (void*)&u2, (void*)&u3, (void*)&u4,
                  (void*)&b0, (void*)&b1, (void*)&b2, (void*)&b3, (void*)&b4,
                  (void*)&hbuf, (void*)&cbuf, (void*)&mbox, (void*)&out};
  hipError_t e = hipLaunchCooperativeKernel((const void*)wavefront_kernel, dim3(grid),
                                            dim3(256), args, 0, stream);
  if (e != hipSuccess) {
    (void)hipGetLastError();  // clear; fall back to plain launch (grid <= capacity)
    wavefront_kernel<<<grid, 256, 0, stream>>>(x, w0, w1, w2, w3, w4, u0, u1, u2, u3, u4,
                                               b0, b1, b2, b3, b4, hbuf, cbuf, mbox, out);
  }
}